// Round 7
// baseline (1639.559 us; speedup 1.0000x reference)
//
#include <hip/hip_runtime.h>
#include <math.h>

using u16 = unsigned short;
typedef __attribute__((ext_vector_type(8))) short short8;
typedef __attribute__((ext_vector_type(4))) float f32x4;

// ---------- bf16 helpers ----------
__device__ __forceinline__ float bf2f(u16 u) {
    union { unsigned int i; float f; } c; c.i = ((unsigned int)u) << 16; return c.f;
}
__device__ __forceinline__ u16 f2bf(float f) {
    union { float f; unsigned int i; } c; c.f = f;
    unsigned int x = c.i;
    x += 0x7fffu + ((x >> 16) & 1u);   // round-to-nearest-even
    return (u16)(x >> 16);
}

#define NE 384
#define NTOK 50176      // 2*8*56*56
#define NTW 98
#define NHEAD 12
#define HD 32

// ---------------------------------------------------------------------------
// LN1 + cyclic shift (-1,-3,-3) + window partition (chunked). wave/token.
// x fp32 in, bf16 out.
// ---------------------------------------------------------------------------
__global__ __launch_bounds__(256) void k_ln1_win(
    const float* __restrict__ x, const float* __restrict__ g, const float* __restrict__ b,
    u16* __restrict__ xw, int wid_off, int nrows)
{
    int widl = blockIdx.x * 4 + (threadIdx.x >> 6);
    int lane = threadIdx.x & 63;
    if (widl >= nrows) return;
    int wid = wid_off + widl;
    int b_ = wid / NTW, n = wid - b_ * NTW;
    int bi = b_ >> 8, widx = b_ & 255;
    int wt = widx >> 6, wh = (widx >> 3) & 7, ww = widx & 7;
    int lt = n / 49; int rr = n - lt * 49; int lh = rr / 7; int lw = rr - lh * 7;
    int t0 = (wt * 2 + lt + 1) & 7;
    int h0 = wh * 7 + lh + 3; if (h0 >= 56) h0 -= 56;
    int w0 = ww * 7 + lw + 3; if (w0 >= 56) w0 -= 56;
    const float* src = x + (size_t)(((bi * 8 + t0) * 56 + h0) * 56 + w0) * NE;

    float v[6]; float s = 0.f, ss = 0.f;
#pragma unroll
    for (int j = 0; j < 6; j++) {
        v[j] = src[lane + j * 64]; s += v[j]; ss += v[j] * v[j];
    }
#pragma unroll
    for (int off = 32; off; off >>= 1) {
        s += __shfl_xor(s, off, 64); ss += __shfl_xor(ss, off, 64);
    }
    float mean = s * (1.0f / 384.0f);
    float var = ss * (1.0f / 384.0f) - mean * mean;
    float rs = rsqrtf(var + 1e-5f);
    u16* dst = xw + (size_t)widl * NE;
#pragma unroll
    for (int j = 0; j < 6; j++) {
        int e = lane + j * 64;
        dst[e] = f2bf((v[j] - mean) * rs * g[e] + b[e]);
    }
}

// ---------------------------------------------------------------------------
// LN2 on fp32 residual (in d_out), bf16 out, chunked
// ---------------------------------------------------------------------------
__global__ __launch_bounds__(256) void k_ln2(
    const float* __restrict__ xres, const float* __restrict__ g, const float* __restrict__ b,
    u16* __restrict__ o, int nrows)
{
    int wid = blockIdx.x * 4 + (threadIdx.x >> 6);
    int lane = threadIdx.x & 63;
    if (wid >= nrows) return;
    const float* src = xres + (size_t)wid * NE;
    float v[6]; float s = 0.f, ss = 0.f;
#pragma unroll
    for (int j = 0; j < 6; j++) {
        v[j] = src[lane + j * 64]; s += v[j]; ss += v[j] * v[j];
    }
#pragma unroll
    for (int off = 32; off; off >>= 1) {
        s += __shfl_xor(s, off, 64); ss += __shfl_xor(ss, off, 64);
    }
    float mean = s * (1.0f / 384.0f);
    float var = ss * (1.0f / 384.0f) - mean * mean;
    float rs = rsqrtf(var + 1e-5f);
    u16* dst = o + (size_t)wid * NE;
#pragma unroll
    for (int j = 0; j < 6; j++) {
        int e = lane + j * 64;
        dst[e] = f2bf((v[j] - mean) * rs * g[e] + b[e]);
    }
}

// ---------------------------------------------------------------------------
// GEMM: C[M,N] = A[M,K](bf16, lda) @ B[K,N](fp32 row-major) + bias(fp32).
// 128x128x32 tiles, 4 waves, mfma 16x16x32 bf16, M predicated.
// MODE 0: bf16 out. MODE 1: window-reverse scatter + x shortcut -> fp32 d_out.
// MODE 2: exact GELU, bf16 out. MODE 3: in-place fp32 residual add (d_out).
// ---------------------------------------------------------------------------
template <int MODE>
__global__ __launch_bounds__(256) void k_gemm(
    const u16* __restrict__ A, int lda, const float* __restrict__ B,
    const float* __restrict__ bias, void* __restrict__ Cv,
    const float* __restrict__ extra, int M, int N, int K, int row_off)
{
    __shared__ __align__(16) u16 As[128][40];
    __shared__ __align__(16) u16 Bs[128][40];
    const int bn = blockIdx.x, bm = blockIdx.y;
    const int tid = threadIdx.x;
    const int lane = tid & 63, wv = tid >> 6;
    const int wr = (wv >> 1) << 6, wc = (wv & 1) << 6;
    const int lm = lane & 15, lg = lane >> 4;

    f32x4 acc[4][4];
#pragma unroll
    for (int a = 0; a < 4; a++)
#pragma unroll
        for (int b = 0; b < 4; b++) acc[a][b] = (f32x4){0.f, 0.f, 0.f, 0.f};

    const int r0 = tid >> 2;            // 0..63
    const int c0 = (tid & 3) << 3;      // 0,8,16,24
    const int rowA0 = bm * 128 + r0, rowA1 = rowA0 + 64;
    const int bk = tid >> 4;            // 0..15
    const int bn8 = (tid & 15) << 3;    // 0..120
    const short8 zero8 = {0, 0, 0, 0, 0, 0, 0, 0};

    for (int kb = 0; kb < K; kb += 32) {
        *(short8*)&As[r0][c0] = (rowA0 < M)
            ? *(const short8*)(A + (size_t)rowA0 * lda + kb + c0) : zero8;
        *(short8*)&As[r0 + 64][c0] = (rowA1 < M)
            ? *(const short8*)(A + (size_t)rowA1 * lda + kb + c0) : zero8;
#pragma unroll
        for (int rep = 0; rep < 2; rep++) {
            int k = bk + rep * 16;
            const float* Bf = B + (size_t)(kb + k) * N + bn * 128 + bn8;
#pragma unroll
            for (int i = 0; i < 8; i++) Bs[bn8 + i][k] = f2bf(Bf[i]);
        }
        __syncthreads();
        short8 fa[4], fb[4];
#pragma unroll
        for (int mt = 0; mt < 4; mt++) fa[mt] = *(const short8*)&As[wr + mt * 16 + lm][lg * 8];
#pragma unroll
        for (int nt = 0; nt < 4; nt++) fb[nt] = *(const short8*)&Bs[wc + nt * 16 + lm][lg * 8];
#pragma unroll
        for (int mt = 0; mt < 4; mt++)
#pragma unroll
            for (int nt = 0; nt < 4; nt++)
                acc[mt][nt] = __builtin_amdgcn_mfma_f32_16x16x32_bf16(
                    fa[mt], fb[nt], acc[mt][nt], 0, 0, 0);
        __syncthreads();
    }

#pragma unroll
    for (int mt = 0; mt < 4; mt++) {
#pragma unroll
        for (int r = 0; r < 4; r++) {
            int row = bm * 128 + wr + mt * 16 + lg * 4 + r;   // local row
            if (row >= M) continue;
            size_t outrow;
            if (MODE == 1) {
                int grow = row + row_off;
                int b_ = grow / NTW, n = grow - b_ * NTW;
                int bi = b_ >> 8, widx = b_ & 255;
                int wt = widx >> 6, wh = (widx >> 3) & 7, ww = widx & 7;
                int lt = n / 49; int rr2 = n - lt * 49; int lh = rr2 / 7; int lw = rr2 - lh * 7;
                int t0 = (wt * 2 + lt + 1) & 7;
                int h0 = wh * 7 + lh + 3; if (h0 >= 56) h0 -= 56;
                int w0 = ww * 7 + lw + 3; if (w0 >= 56) w0 -= 56;
                outrow = (size_t)(((bi * 8 + t0) * 56 + h0) * 56 + w0);
            } else {
                outrow = (size_t)row;
            }
#pragma unroll
            for (int nt = 0; nt < 4; nt++) {
                int col = bn * 128 + wc + nt * 16 + lm;
                float val = acc[mt][nt][r] + bias[col];
                if (MODE == 0) {
                    ((u16*)Cv)[outrow * N + col] = f2bf(val);
                } else if (MODE == 1) {
                    size_t o = outrow * 384 + col;
                    ((float*)Cv)[o] = val + extra[o];
                } else if (MODE == 2) {
                    float gg = 0.5f * val * (1.0f + erff(val * 0.70710678118654752f));
                    ((u16*)Cv)[outrow * N + col] = f2bf(gg);
                } else {
                    size_t o = outrow * N + col;
                    ((float*)Cv)[o] = val + ((float*)Cv)[o];
                }
            }
        }
    }
}

// ---------------------------------------------------------------------------
// Attention per (head, window).  qkv bf16, bias table fp32, out bf16.
// ---------------------------------------------------------------------------
__device__ __forceinline__ float bm_add(int ci, int cj, const float* __restrict__ btab, int h)
{
    int lti = (ci >> 6) & 7, lhi = (ci >> 3) & 7, lwi = ci & 7;
    int ltj = (cj >> 6) & 7, lhj = (cj >> 3) & 7, lwj = cj & 7;
    int idx = (lti - ltj + 1) * 169 + (lhi - lhj + 6) * 13 + (lwi - lwj + 6);
    float v = btab[idx * NHEAD + h];
    if ((ci >> 9) != (cj >> 9)) v -= 100.0f;
    return v;
}

__global__ __launch_bounds__(256) void k_attn(
    const u16* __restrict__ qkv, const float* __restrict__ btab,
    u16* __restrict__ out, int win_off)
{
    __shared__ float Q[98][33];
    __shared__ float KV[98][33];
    __shared__ float S[98][99];
    __shared__ int tc[98];

    const int h = blockIdx.x, bl = blockIdx.y;
    const int tid = threadIdx.x;
    const size_t base = (size_t)bl * NTW * 1152 + (size_t)h * HD;

    for (int idx = tid; idx < 2 * 3136; idx += 256) {
        int part = idx / 3136; int rem = idx - part * 3136;
        int n = rem >> 5, d = rem & 31;
        float v = bf2f(qkv[base + (size_t)n * 1152 + part * 384 + d]);
        if (part == 0) Q[n][d] = v * 0.17677669529663688f;  // 1/sqrt(32)
        else KV[n][d] = v;
    }
    if (tid < NTW) {
        int widx = (bl + win_off) & 255;
        int wt = widx >> 6, wh = (widx >> 3) & 7, ww = widx & 7;
        int lt = tid / 49; int rr = tid - lt * 49; int lh = rr / 7; int lw = rr - lh * 7;
        int t = wt * 2 + lt, hh = wh * 7 + lh, wc2 = ww * 7 + lw;
        int rt = (t < 6) ? 0 : ((t < 7) ? 1 : 2);
        int rh = (hh < 49) ? 0 : ((hh < 53) ? 1 : 2);
        int rw = (wc2 < 49) ? 0 : ((wc2 < 53) ? 1 : 2);
        tc[tid] = (((rt * 3 + rh) * 3 + rw) << 9) | (lt << 6) | (lh << 3) | lw;
    }
    __syncthreads();

    for (int e = tid; e < 2401; e += 256) {
        int pi = e / 49, pj = e - pi * 49;
        int i = pi * 2, j = pj * 2;
        float a00 = 0, a01 = 0, a10 = 0, a11 = 0;
#pragma unroll
        for (int d = 0; d < 32; d++) {
            float q0 = Q[i][d], q1 = Q[i + 1][d];
            float k0 = KV[j][d], k1 = KV[j + 1][d];
            a00 = fmaf(q0, k0, a00); a01 = fmaf(q0, k1, a01);
            a10 = fmaf(q1, k0, a10); a11 = fmaf(q1, k1, a11);
        }
        S[i][j]         = a00 + bm_add(tc[i], tc[j], btab, h);
        S[i][j + 1]     = a01 + bm_add(tc[i], tc[j + 1], btab, h);
        S[i + 1][j]     = a10 + bm_add(tc[i + 1], tc[j], btab, h);
        S[i + 1][j + 1] = a11 + bm_add(tc[i + 1], tc[j + 1], btab, h);
    }
    __syncthreads();

    {
        int wvv = tid >> 6, lane = tid & 63;
        for (int i = wvv; i < 98; i += 4) {
            float s0 = S[i][lane];
            float s1 = (lane < 34) ? S[i][lane + 64] : -1e30f;
            float m = fmaxf(s0, s1);
#pragma unroll
            for (int off = 32; off; off >>= 1) m = fmaxf(m, __shfl_xor(m, off, 64));
            float p0 = __expf(s0 - m);
            float p1 = (lane < 34) ? __expf(s1 - m) : 0.f;
            float sm = p0 + p1;
#pragma unroll
            for (int off = 32; off; off >>= 1) sm += __shfl_xor(sm, off, 64);
            float inv = 1.0f / sm;
            S[i][lane] = p0 * inv;
            if (lane < 34) S[i][lane + 64] = p1 * inv;
        }
    }
    __syncthreads();
    for (int idx = tid; idx < 3136; idx += 256) {
        int n = idx >> 5, d = idx & 31;
        KV[n][d] = bf2f(qkv[base + (size_t)n * 1152 + 768 + d]);
    }
    __syncthreads();

    for (int e = tid; e < 1568; e += 256) {
        int i = (e >> 5) << 1, d = e & 31;
        float a0 = 0, a1 = 0;
        for (int j = 0; j < 98; j++) {
            float vv = KV[j][d];
            a0 = fmaf(S[i][j], vv, a0);
            a1 = fmaf(S[i + 1][j], vv, a1);
        }
        size_t o = ((size_t)bl * NTW + i) * NE + (size_t)h * HD + d;
        out[o] = f2bf(a0);
        out[o + NE] = f2bf(a1);
    }
}

// ---------------------------------------------------------------------------
extern "C" void kernel_launch(void* const* d_in, const int* in_sizes, int n_in,
                              void* d_out, int out_size, void* d_ws, size_t ws_size,
                              hipStream_t stream)
{
    const float* x      = (const float*)d_in[0];
    const float* g1     = (const float*)d_in[1];
    const float* b1     = (const float*)d_in[2];
    const float* qkv_w  = (const float*)d_in[3];
    const float* qkv_b  = (const float*)d_in[4];
    const float* btab   = (const float*)d_in[5];
    const float* proj_w = (const float*)d_in[6];
    const float* proj_b = (const float*)d_in[7];
    const float* g2     = (const float*)d_in[8];
    const float* b2     = (const float*)d_in[9];
    const float* fc1_w  = (const float*)d_in[10];
    const float* fc1_b  = (const float*)d_in[11];
    const float* fc2_w  = (const float*)d_in[12];
    const float* fc2_b  = (const float*)d_in[13];
    float* out = (float*)d_out;          // fp32 output (reference dtype)
    char* ws = (char*)d_ws;

    // per-window bf16 internal footprint (bytes), phases overlaid:
    //   A: xw 75264 + qkv 225792 + attn 75264 = 376320
    //   B: ln2 75264 + hbuf 301056            = 376320
    const size_t per_w = 376320;
    int wpc = 512;
    while (wpc > 1 && (size_t)wpc * per_w > ws_size) wpc >>= 1;

    const int nchunk = 512 / wpc;
    const int rows = wpc * NTW;
    const int mtiles = (rows + 127) / 128;

    u16* xw_c   = (u16*)(ws);
    u16* qkv_c  = (u16*)(ws + (size_t)wpc * 75264);
    u16* attn_c = (u16*)(ws + (size_t)wpc * 301056);
    u16* ln2_c  = (u16*)(ws);
    u16* hbuf_c = (u16*)(ws + (size_t)wpc * 75264);

    // phase A: LN1+shift+window -> qkv -> attn -> proj scatter(+shortcut, fp32)
    for (int c = 0; c < nchunk; c++) {
        int row0 = c * rows;
        k_ln1_win<<<(rows + 3) / 4, 256, 0, stream>>>(x, g1, b1, xw_c, row0, rows);
        k_gemm<0><<<dim3(9, mtiles), 256, 0, stream>>>(
            xw_c, 384, qkv_w, qkv_b, qkv_c, nullptr, rows, 1152, 384, 0);
        k_attn<<<dim3(NHEAD, wpc), 256, 0, stream>>>(qkv_c, btab, attn_c, c * wpc);
        k_gemm<1><<<dim3(3, mtiles), 256, 0, stream>>>(
            attn_c, 384, proj_w, proj_b, out, x, rows, 384, 384, row0);
    }

    // phase B: LN2 -> fc1+GELU -> fc2 (+in-place fp32 residual)
    for (int c = 0; c < nchunk; c++) {
        int row0 = c * rows;
        k_ln2<<<(rows + 3) / 4, 256, 0, stream>>>(out + (size_t)row0 * NE, g2, b2, ln2_c, rows);
        k_gemm<2><<<dim3(12, mtiles), 256, 0, stream>>>(
            ln2_c, 384, fc1_w, fc1_b, hbuf_c, nullptr, rows, 1536, 384, 0);
        k_gemm<3><<<dim3(3, mtiles), 256, 0, stream>>>(
            hbuf_c, 1536, fc2_w, fc2_b, out + (size_t)row0 * NE, nullptr, rows, 384, 1536, 0);
    }
}